// Round 7
// baseline (1961.381 us; speedup 1.0000x reference)
//
#include <hip/hip_runtime.h>
#include <cstdint>
#include <cmath>

// Problem constants (fixed by reference):
//   B=64 examples, D=128 dim, NP=512 nodes/tokens per example, 100 Jacobi Sinkhorn iters.
#define NB_EX 64
#define DIMD 128
#define NP 512
#define NITER 100
constexpr float MARG = 1.0f / 512.0f;   // a = b = 1/n

// ---------- helpers ----------
__device__ __forceinline__ float bf2f_lo(unsigned w) { return __uint_as_float(w << 16); }
__device__ __forceinline__ float bf2f_hi(unsigned w) { return __uint_as_float(w & 0xFFFF0000u); }
__device__ __forceinline__ unsigned short f2bf(float f) {
    unsigned u = __float_as_uint(f);
    u += 0x7FFFu + ((u >> 16) & 1u);      // RTNE
    return (unsigned short)(u >> 16);
}
__device__ __forceinline__ float wred64(float v) {
#pragma unroll
    for (int m = 1; m < 64; m <<= 1) v += __shfl_xor(v, m, 64);
    return v;
}

// Per-block dtype self-detection (bf16-pair low halfword exponent clusters in [110,130];
// fp32 low mantissa bits hit ~8%). 256-thread blocks only. Costs one syncthreads.
__device__ __forceinline__ int self_detect(const unsigned* probe, int t) {
    __shared__ int sd_cnt[4];
    unsigned w = probe[t];
    unsigned e = (w >> 7) & 0xFFu;
    unsigned long long m = __ballot(e >= 110u && e <= 130u);
    if ((t & 63) == 0) sd_cnt[t >> 6] = __popcll(m);
    __syncthreads();
    int c = sd_cnt[0] + sd_cnt[1] + sd_cnt[2] + sd_cnt[3];
    __syncthreads();
    return c >= 128;
}

// ---------- workspace layout (bytes) ----------
#define O_SIMG   0               // 64*64 f32 (16384)
#define O_RNAN   16384           // 32768 f32 (131072)
#define O_RNBN   147456          // 32768 f32 (131072)
#define O_COLP   278528          // 4 banks x 64ex x 4blk x 512 packed u32 (2 MB)
#define O_P0     2375680         // 64*512*512 bf16 (33554432) -> total ~35.9 MB
#define COLP_BANK (64 * 4 * 512) // u32 per bank

// ---------- fused inverse L2 norms for struct_nodes + seq_tokens (65536 rows) ----------
__global__ void k_rnormAB(const void* anr, const void* bnr, float* rnan, float* rnbn) {
    int t = threadIdx.x;
    int flag = self_detect((const unsigned*)anr, t);
    int gr  = blockIdx.x * 4 + (t >> 6);      // global row 0..65535
    int lane = t & 63;
    const void* in = (gr < 32768) ? anr : bnr;
    float* rn      = (gr < 32768) ? rnan : rnbn;
    int row = gr & 32767;
    float f0, f1;
    if (flag) {
        unsigned w = ((const unsigned*)in)[row * 64 + lane];
        f0 = bf2f_lo(w); f1 = bf2f_hi(w);
    } else {
        float2 v = ((const float2*)in)[row * 64 + lane];
        f0 = v.x; f1 = v.y;
    }
    float ss = wred64(f0 * f0 + f1 * f1);
    if (lane == 0) rn[row] = 1.0f / fmaxf(sqrtf(ss), 1e-12f);
}

// ---------- global sim logits (self-detecting, self-normalizing) ----------
__global__ void k_simg(const void* sgr, const void* qgr, float* simg) {
    __shared__ float rls[128];                // [0..63]=1/||s_i||, [64..127]=1/||q_j||
    int t = threadIdx.x;
    int flag = self_detect((const unsigned*)sgr, t);
    int w = t >> 6, lane = t & 63;
    for (int rr = 0; rr < 32; rr++) {         // each wave: 32 of 128 rows
        int ri = w * 32 + rr;
        const void* base = (ri < 64) ? sgr : qgr;
        int row = ri & 63;
        float f0, f1;
        if (flag) {
            unsigned wd = ((const unsigned*)base)[row * 64 + lane];
            f0 = bf2f_lo(wd); f1 = bf2f_hi(wd);
        } else {
            float2 v = ((const float2*)base)[row * 64 + lane];
            f0 = v.x; f1 = v.y;
        }
        float ss = wred64(f0 * f0 + f1 * f1);
        if (lane == 0) rls[ri] = 1.0f / fmaxf(sqrtf(ss), 1e-12f);
    }
    __syncthreads();
    int g = blockIdx.x * 256 + t;             // 4096 = 64*64
    int i = g >> 6, j = g & 63;
    float dot = 0.f;
    if (flag) {
        const unsigned* a = (const unsigned*)sgr + i * 64;
        const unsigned* b = (const unsigned*)qgr + j * 64;
        for (int k = 0; k < 64; k++) {
            unsigned wa = a[k], wb = b[k];
            dot += bf2f_lo(wa) * bf2f_lo(wb);
            dot += bf2f_hi(wa) * bf2f_hi(wb);
        }
    } else {
        const float4* a = (const float4*)sgr + i * 32;
        const float4* b = (const float4*)qgr + j * 32;
        for (int k = 0; k < 32; k++) {
            float4 x = a[k], y = b[k];
            dot += x.x * y.x + x.y * y.y + x.z * y.z + x.w * y.w;
        }
    }
    simg[g] = dot * rls[i] * rls[64 + j] * 10.0f;   // /TEMP = *10
}

// ---------- global NT-Xent; initializes all 3 outputs (stores, not adds) ----------
__global__ void k_gloss(const float* __restrict__ simg, float* outf) {
    __shared__ float red[64];
    int i = threadIdx.x;
    if (i < 64) {
        float m = -1e30f;
        for (int j = 0; j < 64; j++) m = fmaxf(m, simg[i * 64 + j]);
        float se = 0.f;
        for (int j = 0; j < 64; j++) se += expf(simg[i * 64 + j] - m);
        float rl = simg[i * 64 + i] - (m + logf(se));
        float m2 = -1e30f;
        for (int j = 0; j < 64; j++) m2 = fmaxf(m2, simg[j * 64 + i]);
        float se2 = 0.f;
        for (int j = 0; j < 64; j++) se2 += expf(simg[j * 64 + i] - m2);
        float cl = simg[i * 64 + i] - (m2 + logf(se2));
        red[i] = rl + cl;
    }
    __syncthreads();
    if (i == 0) {
        float s = 0.f;
        for (int k = 0; k < 64; k++) s += red[k];
        float g = -s / 128.0f;
        outf[0] = g;          // global loss
        outf[1] = 0.0f;       // local loss accumulated by k_persist
        outf[2] = g;          // total = g + local (added by k_persist)
    }
}

// ---------- build P0 = exp(10*sim) bf16, per-example 512x512, 128x128 tiles ----------
__global__ void k_build(const void* anr, const void* bnr, const float* rnan, const float* rnbn,
                        unsigned short* p0) {
    int t  = threadIdx.x;
    int flag = self_detect((const unsigned*)anr, t);
    int b   = blockIdx.y;
    int r0t = (blockIdx.x >> 2) * 128;
    int c0t = (blockIdx.x & 3) * 128;
    __shared__ float As[128][33];
    __shared__ float Bs[128][33];
    int tr = t >> 4, tc = t & 15;
    float acc[8][8];
#pragma unroll
    for (int i = 0; i < 8; i++)
#pragma unroll
        for (int j = 0; j < 8; j++) acc[i][j] = 0.f;

    for (int kc = 0; kc < 4; kc++) {            // K chunks of 32
        for (int ii = 0; ii < 4; ii++) {
            int idx = t + 256 * ii;             // 0..1023 -> 128 rows x 8 float4
            int r = idx >> 3, c4 = idx & 7;
            {   // A chunk (struct_nodes)
                int grow = b * NP + r0t + r;
                float sc = rnan[grow];
                float f0, f1, f2, f3;
                if (flag) {
                    const unsigned* src = (const unsigned*)anr + ((grow * DIMD + kc * 32 + c4 * 4) >> 1);
                    unsigned w0 = src[0], w1 = src[1];
                    f0 = bf2f_lo(w0); f1 = bf2f_hi(w0); f2 = bf2f_lo(w1); f3 = bf2f_hi(w1);
                } else {
                    float4 v = *((const float4*)((const float*)anr + grow * DIMD + kc * 32 + c4 * 4));
                    f0 = v.x; f1 = v.y; f2 = v.z; f3 = v.w;
                }
                As[r][c4 * 4 + 0] = f0 * sc; As[r][c4 * 4 + 1] = f1 * sc;
                As[r][c4 * 4 + 2] = f2 * sc; As[r][c4 * 4 + 3] = f3 * sc;
            }
            {   // B chunk (seq_tokens)
                int grow = b * NP + c0t + r;
                float sc = rnbn[grow];
                float f0, f1, f2, f3;
                if (flag) {
                    const unsigned* src = (const unsigned*)bnr + ((grow * DIMD + kc * 32 + c4 * 4) >> 1);
                    unsigned w0 = src[0], w1 = src[1];
                    f0 = bf2f_lo(w0); f1 = bf2f_hi(w0); f2 = bf2f_lo(w1); f3 = bf2f_hi(w1);
                } else {
                    float4 v = *((const float4*)((const float*)bnr + grow * DIMD + kc * 32 + c4 * 4));
                    f0 = v.x; f1 = v.y; f2 = v.z; f3 = v.w;
                }
                Bs[r][c4 * 4 + 0] = f0 * sc; Bs[r][c4 * 4 + 1] = f1 * sc;
                Bs[r][c4 * 4 + 2] = f2 * sc; Bs[r][c4 * 4 + 3] = f3 * sc;
            }
        }
        __syncthreads();
        for (int kk = 0; kk < 32; kk++) {
            float av[8], bv[8];
#pragma unroll
            for (int i = 0; i < 8; i++) av[i] = As[tr * 8 + i][kk];
#pragma unroll
            for (int j = 0; j < 8; j++) bv[j] = Bs[tc * 8 + j][kk];
#pragma unroll
            for (int i = 0; i < 8; i++)
#pragma unroll
                for (int j = 0; j < 8; j++) acc[i][j] += av[i] * bv[j];
        }
        __syncthreads();
    }
#pragma unroll
    for (int i = 0; i < 8; i++) {
        int grow = b * NP + r0t + tr * 8 + i;
        unsigned short h[8];
#pragma unroll
        for (int j = 0; j < 8; j++) h[j] = f2bf(expf(acc[i][j] * 10.0f));   // exp(sim/REG)
        uint4 pk;
        pk.x = (unsigned)h[0] | ((unsigned)h[1] << 16);
        pk.y = (unsigned)h[2] | ((unsigned)h[3] << 16);
        pk.z = (unsigned)h[4] | ((unsigned)h[5] << 16);
        pk.w = (unsigned)h[6] | ((unsigned)h[7] << 16);
        *((uint4*)(p0 + ((size_t)grow * NP + c0t + tc * 8))) = pk;
    }
}

// ---------- persistent Sinkhorn: software-pipelined exchange ----------
// R6 lesson: exchange latency (~4.5 us) sits on the critical path of every iteration.
// Jacobi = two independent chains (u_{k+1}=f(v_k), v_{k+1}=g(u_k)), so reorder each iter:
//   [col pass (u_k) -> store tag k+1 -> poll tag k -> row pass (v_k) -> u_{k+1}]
// Partials for v_{k+1} are in flight a FULL iteration before any reader polls them:
// steady-state period = (compute + latency)/2.
// Layout: 4 blocks x 512 thr per example (256 blocks ~ 1/CU). Lane owns cols {l+64k}
// (strided; set up via one-time LDS redistribution) -> colred/v_s LDS accesses are
// conflict-free. P0 slice lives as fp32 f[16][8] = 128 VGPRs (launch_bounds(512,2)).
// Tag banks = 4 (REQUIRED with store-before-poll order): poll(k-1) success => peers
// finished iter k-2 => peers fully completed iter k-3 incl. its poll => tag k-3 slots
// dead => mod-4 overwrite is race-free and deadlock-free. Stale d_ws is 0xAA-poisoned
// => tag field 0xAAAA never collides with tags 1..100 (no memset needed).
__global__ __launch_bounds__(512, 2) void k_persist(const unsigned short* __restrict__ p0,
                                                    unsigned* __restrict__ colp,
                                                    float* __restrict__ outf) {
    int blk = blockIdx.x;
    int b   = blk >> 2;         // example
    int rb  = blk & 3;          // rowblock 0..3
    int rowbase = rb * 128;
    int t = threadIdx.x, w = t >> 6, lane = t & 63;

    __shared__ float colred[8][512];
    __shared__ float v_s[512];
    __shared__ float bs[8];

    // --- one-time: load P0 slice (coalesced uint4) and redistribute so lane owns
    //     cols {lane + 64k}; keep fp32 in registers for the whole kernel.
    float f[16][8];
#pragma unroll 1
    for (int r = 0; r < 16; ++r) {
        int row = rowbase + w * 16 + r;
        uint4 pv = ((const uint4*)(p0 + (((size_t)(b << 9) + row) << 9)))[lane];
        colred[w][lane * 8 + 0] = bf2f_lo(pv.x);
        colred[w][lane * 8 + 1] = bf2f_hi(pv.x);
        colred[w][lane * 8 + 2] = bf2f_lo(pv.y);
        colred[w][lane * 8 + 3] = bf2f_hi(pv.y);
        colred[w][lane * 8 + 4] = bf2f_lo(pv.z);
        colred[w][lane * 8 + 5] = bf2f_hi(pv.z);
        colred[w][lane * 8 + 6] = bf2f_lo(pv.w);
        colred[w][lane * 8 + 7] = bf2f_hi(pv.w);
        __syncthreads();
#pragma unroll
        for (int k = 0; k < 8; ++k) f[r][k] = colred[w][lane + (k << 6)];
        __syncthreads();
    }

    float u_loc[16];
#pragma unroll
    for (int r = 0; r < 16; ++r) u_loc[r] = MARG;   // u_0 = a = 1/n

#pragma unroll 1
    for (int it = 0; it < NITER; ++it) {
        // ---- col pass: partials of P0^T u_it (produces v_{it+1} remotely) ----
        float ca[8];
#pragma unroll
        for (int k = 0; k < 8; ++k) ca[k] = 0.f;
#pragma unroll
        for (int r = 0; r < 16; ++r) {
            float u_r = u_loc[r];
#pragma unroll
            for (int k = 0; k < 8; ++k) ca[k] += f[r][k] * u_r;
        }
#pragma unroll
        for (int k = 0; k < 8; ++k) colred[w][lane + (k << 6)] = ca[k];
        __syncthreads();
        // ---- store tagged partial for col t (fire-and-forget) ----
        unsigned tag_w = (unsigned)(it + 1);
        {
            float s = colred[0][t] + colred[1][t] + colred[2][t] + colred[3][t]
                    + colred[4][t] + colred[5][t] + colred[6][t] + colred[7][t];
            unsigned pkw = ((unsigned)f2bf(s) << 16) | tag_w;
            unsigned* cw = colp + (((((it + 1) & 3) * 64 + b) * 4 + rb) << 9) + t;
            __hip_atomic_store(cw, pkw, __ATOMIC_RELAXED, __HIP_MEMORY_SCOPE_AGENT);
        }
        // ---- poll v_it (tag it), stored by peers one iteration ago ----
        float q;
        if (it == 0) {
            q = MARG;                              // v_0 = b = 1/n
        } else {
            unsigned tag = (unsigned)it;
            const unsigned* crd = colp + ((((it & 3) * 64 + b) * 4) << 9) + t;
            unsigned g0, g1, g2, g3;
            for (;;) {
                g0 = __hip_atomic_load(&crd[0 << 9], __ATOMIC_RELAXED, __HIP_MEMORY_SCOPE_AGENT);
                g1 = __hip_atomic_load(&crd[1 << 9], __ATOMIC_RELAXED, __HIP_MEMORY_SCOPE_AGENT);
                g2 = __hip_atomic_load(&crd[2 << 9], __ATOMIC_RELAXED, __HIP_MEMORY_SCOPE_AGENT);
                g3 = __hip_atomic_load(&crd[3 << 9], __ATOMIC_RELAXED, __HIP_MEMORY_SCOPE_AGENT);
                if (((g0 & 0xFFFFu) == tag) && ((g1 & 0xFFFFu) == tag) &&
                    ((g2 & 0xFFFFu) == tag) && ((g3 & 0xFFFFu) == tag)) break;
                __builtin_amdgcn_s_sleep(1);
            }
            float raw = __uint_as_float(g0 & 0xFFFF0000u) + __uint_as_float(g1 & 0xFFFF0000u)
                      + __uint_as_float(g2 & 0xFFFF0000u) + __uint_as_float(g3 & 0xFFFF0000u);
            q = MARG / raw;
            if (!isfinite(q)) q = MARG;            // nan_to_num
        }
        v_s[t] = q;
        __syncthreads();
        // ---- row pass: u_{it+1} = a / (P0 v_it), kept per-lane in registers ----
        float vr[8];
#pragma unroll
        for (int k = 0; k < 8; ++k) vr[k] = v_s[lane + (k << 6)];
#pragma unroll
        for (int r = 0; r < 16; ++r) {
            float rd = 0.f;
#pragma unroll
            for (int k = 0; k < 8; ++k) rd += f[r][k] * vr[k];
            rd = wred64(rd);                       // all lanes hold the row sum
            float qq = MARG / rd;
            if (!isfinite(qq)) qq = MARG;
            u_loc[r] = qq;
        }
    }

    // ---- v_100 from tag 100, then final contraction: sum u p v * (-0.1 log p) ----
    {
        unsigned tag = 100u;
        const unsigned* crd = colp + ((((100 & 3) * 64 + b) * 4) << 9) + t;
        unsigned g0, g1, g2, g3;
        for (;;) {
            g0 = __hip_atomic_load(&crd[0 << 9], __ATOMIC_RELAXED, __HIP_MEMORY_SCOPE_AGENT);
            g1 = __hip_atomic_load(&crd[1 << 9], __ATOMIC_RELAXED, __HIP_MEMORY_SCOPE_AGENT);
            g2 = __hip_atomic_load(&crd[2 << 9], __ATOMIC_RELAXED, __HIP_MEMORY_SCOPE_AGENT);
            g3 = __hip_atomic_load(&crd[3 << 9], __ATOMIC_RELAXED, __HIP_MEMORY_SCOPE_AGENT);
            if (((g0 & 0xFFFFu) == tag) && ((g1 & 0xFFFFu) == tag) &&
                ((g2 & 0xFFFFu) == tag) && ((g3 & 0xFFFFu) == tag)) break;
            __builtin_amdgcn_s_sleep(1);
        }
        float raw = __uint_as_float(g0 & 0xFFFF0000u) + __uint_as_float(g1 & 0xFFFF0000u)
                  + __uint_as_float(g2 & 0xFFFF0000u) + __uint_as_float(g3 & 0xFFFF0000u);
        float q = MARG / raw;
        if (!isfinite(q)) q = MARG;
        v_s[t] = q;
    }
    __syncthreads();
    float vr[8];
#pragma unroll
    for (int k = 0; k < 8; ++k) vr[k] = v_s[lane + (k << 6)];
    float acc = 0.f;
#pragma unroll
    for (int r = 0; r < 16; ++r) {
        float u_r = u_loc[r];
#pragma unroll
        for (int k = 0; k < 8; ++k) {
            float p = f[r][k];
            acc += u_r * p * vr[k] * (-0.1f) * logf(p);   // C = -log(P0)/10
        }
    }
    acc = wred64(acc);
    if (lane == 0) bs[w] = acc;
    __syncthreads();
    if (t == 0) {
        float c = (bs[0] + bs[1] + bs[2] + bs[3] + bs[4] + bs[5] + bs[6] + bs[7])
                  * (1.0f / 64.0f);               // /B
        atomicAdd(&outf[1], c);
        atomicAdd(&outf[2], c);
    }
}

extern "C" void kernel_launch(void* const* d_in, const int* in_sizes, int n_in,
                              void* d_out, int out_size, void* d_ws, size_t ws_size,
                              hipStream_t stream) {
    const void* sg = d_in[0];
    const void* qg = d_in[1];
    const void* an = d_in[2];
    const void* bn = d_in[3];
    char* ws = (char*)d_ws;
    float* outf = (float*)d_out;                     // output dtype: float32 x3

    float* simg     = (float*)(ws + O_SIMG);
    float* rnan     = (float*)(ws + O_RNAN);
    float* rnbn     = (float*)(ws + O_RNBN);
    unsigned* colp  = (unsigned*)(ws + O_COLP);      // 4 tagged banks
    unsigned short* p0 = (unsigned short*)(ws + O_P0);

    k_rnormAB<<<16384, 256, 0, stream>>>(an, bn, rnan, rnbn);
    k_simg<<<16, 256, 0, stream>>>(sg, qg, simg);
    k_gloss<<<1, 256, 0, stream>>>(simg, outf);
    k_build<<<dim3(16, 64), 256, 0, stream>>>(an, bn, rnan, rnbn, p0);
    k_persist<<<256, 512, 0, stream>>>(p0, colp, outf);
}

// Round 8
// 760.835 us; speedup vs baseline: 2.5779x; 2.5779x over previous
//
#include <hip/hip_runtime.h>
#include <cstdint>
#include <cmath>

// Problem constants (fixed by reference):
//   B=64 examples, D=128 dim, NP=512 nodes/tokens per example, 100 Jacobi Sinkhorn iters.
#define NB_EX 64
#define DIMD 128
#define NP 512
#define NITER 100
constexpr float MARG = 1.0f / 512.0f;   // a = b = 1/n

// ---------- helpers ----------
__device__ __forceinline__ float bf2f_lo(unsigned w) { return __uint_as_float(w << 16); }
__device__ __forceinline__ float bf2f_hi(unsigned w) { return __uint_as_float(w & 0xFFFF0000u); }
__device__ __forceinline__ unsigned short f2bf(float f) {
    unsigned u = __float_as_uint(f);
    u += 0x7FFFu + ((u >> 16) & 1u);      // RTNE
    return (unsigned short)(u >> 16);
}
__device__ __forceinline__ float wred64(float v) {
#pragma unroll
    for (int m = 1; m < 64; m <<= 1) v += __shfl_xor(v, m, 64);
    return v;
}

// Per-block dtype self-detection (bf16-pair low halfword exponent clusters in [110,130];
// fp32 low mantissa bits hit ~8%). 256-thread blocks only. Costs one syncthreads.
__device__ __forceinline__ int self_detect(const unsigned* probe, int t) {
    __shared__ int sd_cnt[4];
    unsigned w = probe[t];
    unsigned e = (w >> 7) & 0xFFu;
    unsigned long long m = __ballot(e >= 110u && e <= 130u);
    if ((t & 63) == 0) sd_cnt[t >> 6] = __popcll(m);
    __syncthreads();
    int c = sd_cnt[0] + sd_cnt[1] + sd_cnt[2] + sd_cnt[3];
    __syncthreads();
    return c >= 128;
}

// ---------- workspace layout (bytes) ----------
#define O_SIMG   0               // 64*64 f32 (16384)
#define O_RNAN   16384           // 32768 f32 (131072)
#define O_RNBN   147456          // 32768 f32 (131072)
#define O_COLP   278528          // 4 banks x 64ex x 8blk x 512 packed u32 (4 MB)
#define O_P0     4472832         // 64*512*512 bf16 (33554432) -> total ~38 MB
#define COLP_BANK (64 * 8 * 512) // u32 per bank

// ---------- fused inverse L2 norms for struct_nodes + seq_tokens (65536 rows) ----------
__global__ void k_rnormAB(const void* anr, const void* bnr, float* rnan, float* rnbn) {
    int t = threadIdx.x;
    int flag = self_detect((const unsigned*)anr, t);
    int gr  = blockIdx.x * 4 + (t >> 6);      // global row 0..65535
    int lane = t & 63;
    const void* in = (gr < 32768) ? anr : bnr;
    float* rn      = (gr < 32768) ? rnan : rnbn;
    int row = gr & 32767;
    float f0, f1;
    if (flag) {
        unsigned w = ((const unsigned*)in)[row * 64 + lane];
        f0 = bf2f_lo(w); f1 = bf2f_hi(w);
    } else {
        float2 v = ((const float2*)in)[row * 64 + lane];
        f0 = v.x; f1 = v.y;
    }
    float ss = wred64(f0 * f0 + f1 * f1);
    if (lane == 0) rn[row] = 1.0f / fmaxf(sqrtf(ss), 1e-12f);
}

// ---------- global sim logits (self-detecting, self-normalizing) ----------
__global__ void k_simg(const void* sgr, const void* qgr, float* simg) {
    __shared__ float rls[128];                // [0..63]=1/||s_i||, [64..127]=1/||q_j||
    int t = threadIdx.x;
    int flag = self_detect((const unsigned*)sgr, t);
    int w = t >> 6, lane = t & 63;
    for (int rr = 0; rr < 32; rr++) {         // each wave: 32 of 128 rows
        int ri = w * 32 + rr;
        const void* base = (ri < 64) ? sgr : qgr;
        int row = ri & 63;
        float f0, f1;
        if (flag) {
            unsigned wd = ((const unsigned*)base)[row * 64 + lane];
            f0 = bf2f_lo(wd); f1 = bf2f_hi(wd);
        } else {
            float2 v = ((const float2*)base)[row * 64 + lane];
            f0 = v.x; f1 = v.y;
        }
        float ss = wred64(f0 * f0 + f1 * f1);
        if (lane == 0) rls[ri] = 1.0f / fmaxf(sqrtf(ss), 1e-12f);
    }
    __syncthreads();
    int g = blockIdx.x * 256 + t;             // 4096 = 64*64
    int i = g >> 6, j = g & 63;
    float dot = 0.f;
    if (flag) {
        const unsigned* a = (const unsigned*)sgr + i * 64;
        const unsigned* b = (const unsigned*)qgr + j * 64;
        for (int k = 0; k < 64; k++) {
            unsigned wa = a[k], wb = b[k];
            dot += bf2f_lo(wa) * bf2f_lo(wb);
            dot += bf2f_hi(wa) * bf2f_hi(wb);
        }
    } else {
        const float4* a = (const float4*)sgr + i * 32;
        const float4* b = (const float4*)qgr + j * 32;
        for (int k = 0; k < 32; k++) {
            float4 x = a[k], y = b[k];
            dot += x.x * y.x + x.y * y.y + x.z * y.z + x.w * y.w;
        }
    }
    simg[g] = dot * rls[i] * rls[64 + j] * 10.0f;   // /TEMP = *10
}

// ---------- global NT-Xent; initializes all 3 outputs (stores, not adds) ----------
__global__ void k_gloss(const float* __restrict__ simg, float* outf) {
    __shared__ float red[64];
    int i = threadIdx.x;
    if (i < 64) {
        float m = -1e30f;
        for (int j = 0; j < 64; j++) m = fmaxf(m, simg[i * 64 + j]);
        float se = 0.f;
        for (int j = 0; j < 64; j++) se += expf(simg[i * 64 + j] - m);
        float rl = simg[i * 64 + i] - (m + logf(se));
        float m2 = -1e30f;
        for (int j = 0; j < 64; j++) m2 = fmaxf(m2, simg[j * 64 + i]);
        float se2 = 0.f;
        for (int j = 0; j < 64; j++) se2 += expf(simg[j * 64 + i] - m2);
        float cl = simg[i * 64 + i] - (m2 + logf(se2));
        red[i] = rl + cl;
    }
    __syncthreads();
    if (i == 0) {
        float s = 0.f;
        for (int k = 0; k < 64; k++) s += red[k];
        float g = -s / 128.0f;
        outf[0] = g;          // global loss
        outf[1] = 0.0f;       // local loss accumulated by k_persist
        outf[2] = g;          // total = g + local (added by k_persist)
    }
}

// ---------- build P0 = exp(10*sim) bf16, per-example 512x512, 128x128 tiles ----------
__global__ void k_build(const void* anr, const void* bnr, const float* rnan, const float* rnbn,
                        unsigned short* p0) {
    int t  = threadIdx.x;
    int flag = self_detect((const unsigned*)anr, t);
    int b   = blockIdx.y;
    int r0t = (blockIdx.x >> 2) * 128;
    int c0t = (blockIdx.x & 3) * 128;
    __shared__ float As[128][33];
    __shared__ float Bs[128][33];
    int tr = t >> 4, tc = t & 15;
    float acc[8][8];
#pragma unroll
    for (int i = 0; i < 8; i++)
#pragma unroll
        for (int j = 0; j < 8; j++) acc[i][j] = 0.f;

    for (int kc = 0; kc < 4; kc++) {            // K chunks of 32
        for (int ii = 0; ii < 4; ii++) {
            int idx = t + 256 * ii;             // 0..1023 -> 128 rows x 8 float4
            int r = idx >> 3, c4 = idx & 7;
            {   // A chunk (struct_nodes)
                int grow = b * NP + r0t + r;
                float sc = rnan[grow];
                float f0, f1, f2, f3;
                if (flag) {
                    const unsigned* src = (const unsigned*)anr + ((grow * DIMD + kc * 32 + c4 * 4) >> 1);
                    unsigned w0 = src[0], w1 = src[1];
                    f0 = bf2f_lo(w0); f1 = bf2f_hi(w0); f2 = bf2f_lo(w1); f3 = bf2f_hi(w1);
                } else {
                    float4 v = *((const float4*)((const float*)anr + grow * DIMD + kc * 32 + c4 * 4));
                    f0 = v.x; f1 = v.y; f2 = v.z; f3 = v.w;
                }
                As[r][c4 * 4 + 0] = f0 * sc; As[r][c4 * 4 + 1] = f1 * sc;
                As[r][c4 * 4 + 2] = f2 * sc; As[r][c4 * 4 + 3] = f3 * sc;
            }
            {   // B chunk (seq_tokens)
                int grow = b * NP + c0t + r;
                float sc = rnbn[grow];
                float f0, f1, f2, f3;
                if (flag) {
                    const unsigned* src = (const unsigned*)bnr + ((grow * DIMD + kc * 32 + c4 * 4) >> 1);
                    unsigned w0 = src[0], w1 = src[1];
                    f0 = bf2f_lo(w0); f1 = bf2f_hi(w0); f2 = bf2f_lo(w1); f3 = bf2f_hi(w1);
                } else {
                    float4 v = *((const float4*)((const float*)bnr + grow * DIMD + kc * 32 + c4 * 4));
                    f0 = v.x; f1 = v.y; f2 = v.z; f3 = v.w;
                }
                Bs[r][c4 * 4 + 0] = f0 * sc; Bs[r][c4 * 4 + 1] = f1 * sc;
                Bs[r][c4 * 4 + 2] = f2 * sc; Bs[r][c4 * 4 + 3] = f3 * sc;
            }
        }
        __syncthreads();
        for (int kk = 0; kk < 32; kk++) {
            float av[8], bv[8];
#pragma unroll
            for (int i = 0; i < 8; i++) av[i] = As[tr * 8 + i][kk];
#pragma unroll
            for (int j = 0; j < 8; j++) bv[j] = Bs[tc * 8 + j][kk];
#pragma unroll
            for (int i = 0; i < 8; i++)
#pragma unroll
                for (int j = 0; j < 8; j++) acc[i][j] += av[i] * bv[j];
        }
        __syncthreads();
    }
#pragma unroll
    for (int i = 0; i < 8; i++) {
        int grow = b * NP + r0t + tr * 8 + i;
        unsigned short h[8];
#pragma unroll
        for (int j = 0; j < 8; j++) h[j] = f2bf(expf(acc[i][j] * 10.0f));   // exp(sim/REG)
        uint4 pk;
        pk.x = (unsigned)h[0] | ((unsigned)h[1] << 16);
        pk.y = (unsigned)h[2] | ((unsigned)h[3] << 16);
        pk.z = (unsigned)h[4] | ((unsigned)h[5] << 16);
        pk.w = (unsigned)h[6] | ((unsigned)h[7] << 16);
        *((uint4*)(p0 + ((size_t)grow * NP + c0t + tc * 8))) = pk;
    }
}

// ---------- persistent Sinkhorn: R7 pipelined schedule on R6's no-spill layout ----------
// R7 lesson: fp32 f[16][8] (128 regs) + launch_bounds(512,2) (128-VGPR budget) = full spill
// to scratch (VGPR_Count 52, FETCH 6.2 GB). Fix: P0 stays PACKED bf16 uint4 pw[16] = 64
// VGPRs (R6 compiled clean at 96 total); 256-thr blocks, 8 blocks/example, 2 blocks/CU.
// Schedule per iter (pipelined exchange, R7 idea):
//   [col pass (u_it) -> fire store tag it+1] -> [poll tag it] -> [row pass -> u_{it+1}]
// Tag-k data is stored a full iteration before anyone polls it -> polls hit first try.
// u lives in registers (wred64 leaves the row sum in ALL lanes) -> no u LDS, 2 syncs/iter.
// Mod-4 tag banks REQUIRED (store-before-poll): poll(k-1) success => peers finished iter
// k-2 => their iter k-3 poll done => tag k-3 slots dead => mod-4 overwrite race-free.
// Stale-tag safety: d_ws re-poisoned 0xAA => tag field 0xAAAA never in {1..100}.
__global__ __launch_bounds__(256, 2) void k_persist(const unsigned short* __restrict__ p0,
                                                    unsigned* __restrict__ colp,
                                                    float* __restrict__ outf) {
    int blk = blockIdx.x;
    int rb  = blk >> 6;         // 0..7 (blocks of one example share blk%8 -> same XCD)
    int b   = blk & 63;         // example
    int rowbase = rb * 64;
    int t = threadIdx.x, w = t >> 6, lane = t & 63;

    __shared__ float colred[4][512];
    __shared__ float v_s[512];
    __shared__ float bs[4];

    // load this lane's static P0 slice into registers (only global P0 read of the kernel)
    uint4 pw[16];
#pragma unroll
    for (int r = 0; r < 16; r++) {
        int row = rowbase + w * 16 + r;
        pw[r] = ((const uint4*)(p0 + (((size_t)(b << 9) + row) << 9)))[lane];
    }
    float u_loc[16];
#pragma unroll
    for (int r = 0; r < 16; r++) u_loc[r] = MARG;   // u_0 = a = 1/n

    int col0 = t, col1 = t + 256;

#pragma unroll 1
    for (int it = 0; it < NITER; ++it) {
        // ---- col pass: partials of P0^T u_it (feeds v_{it+1} remotely) ----
        float ca[8];
#pragma unroll
        for (int k = 0; k < 8; ++k) ca[k] = 0.f;
#pragma unroll
        for (int r = 0; r < 16; ++r) {
            float u_r = u_loc[r];
            uint4 pv = pw[r];
            ca[0] += bf2f_lo(pv.x) * u_r; ca[1] += bf2f_hi(pv.x) * u_r;
            ca[2] += bf2f_lo(pv.y) * u_r; ca[3] += bf2f_hi(pv.y) * u_r;
            ca[4] += bf2f_lo(pv.z) * u_r; ca[5] += bf2f_hi(pv.z) * u_r;
            ca[6] += bf2f_lo(pv.w) * u_r; ca[7] += bf2f_hi(pv.w) * u_r;
        }
#pragma unroll
        for (int k = 0; k < 8; ++k) colred[w][lane * 8 + k] = ca[k];
        __syncthreads();
        // ---- fire-and-forget tagged partials (2 cols per thread) ----
        unsigned tag_w = (unsigned)(it + 1);
        {
            float s0 = colred[0][col0] + colred[1][col0] + colred[2][col0] + colred[3][col0];
            float s1 = colred[0][col1] + colred[1][col1] + colred[2][col1] + colred[3][col1];
            unsigned p0w = ((unsigned)f2bf(s0) << 16) | tag_w;
            unsigned p1w = ((unsigned)f2bf(s1) << 16) | tag_w;
            unsigned* cw = colp + (((((it + 1) & 3) * 64 + b) * 8 + rb) << 9);
            __hip_atomic_store(&cw[col0], p0w, __ATOMIC_RELAXED, __HIP_MEMORY_SCOPE_AGENT);
            __hip_atomic_store(&cw[col1], p1w, __ATOMIC_RELAXED, __HIP_MEMORY_SCOPE_AGENT);
        }
        // ---- poll v_it (tag it) — stored by peers one full iteration ago ----
        if (it == 0) {
            v_s[col0] = MARG;                      // v_0 = b = 1/n
            v_s[col1] = MARG;
        } else {
            unsigned tag = (unsigned)it;
            const unsigned* crd = colp + ((((it & 3) * 64 + b) * 8) << 9);
            unsigned got0[8], got1[8];
            for (;;) {
                bool o = true;
#pragma unroll
                for (int p = 0; p < 8; p++) {
                    got0[p] = __hip_atomic_load(&crd[(p << 9) + col0], __ATOMIC_RELAXED,
                                                __HIP_MEMORY_SCOPE_AGENT);
                    got1[p] = __hip_atomic_load(&crd[(p << 9) + col1], __ATOMIC_RELAXED,
                                                __HIP_MEMORY_SCOPE_AGENT);
                }
#pragma unroll
                for (int p = 0; p < 8; p++)
                    o = o && ((got0[p] & 0xFFFFu) == tag) && ((got1[p] & 0xFFFFu) == tag);
                if (o) break;
                __builtin_amdgcn_s_sleep(1);
            }
            float r0 = 0.f, r1 = 0.f;
#pragma unroll
            for (int p = 0; p < 8; p++) {
                r0 += __uint_as_float(got0[p] & 0xFFFF0000u);
                r1 += __uint_as_float(got1[p] & 0xFFFF0000u);
            }
            float q0 = MARG / r0; if (!isfinite(q0)) q0 = MARG;
            float q1 = MARG / r1; if (!isfinite(q1)) q1 = MARG;
            v_s[col0] = q0;
            v_s[col1] = q1;
        }
        __syncthreads();
        // ---- row pass: u_{it+1} = a / (P0 v_it), all-lane row sums via wred64 ----
        float vr[8];
#pragma unroll
        for (int k = 0; k < 8; ++k) vr[k] = v_s[lane * 8 + k];
#pragma unroll
        for (int r = 0; r < 16; ++r) {
            uint4 pv = pw[r];
            float rd = bf2f_lo(pv.x) * vr[0] + bf2f_hi(pv.x) * vr[1]
                     + bf2f_lo(pv.y) * vr[2] + bf2f_hi(pv.y) * vr[3]
                     + bf2f_lo(pv.z) * vr[4] + bf2f_hi(pv.z) * vr[5]
                     + bf2f_lo(pv.w) * vr[6] + bf2f_hi(pv.w) * vr[7];
            rd = wred64(rd);                       // all lanes hold the row sum
            float qq = MARG / rd;
            if (!isfinite(qq)) qq = MARG;
            u_loc[r] = qq;
        }
    }

    // ---- v_100 (tag 100, bank 0), then final contraction ----
    {
        unsigned tag = 100u;
        const unsigned* crd = colp + (((0 * 64 + b) * 8) << 9);
        unsigned got0[8], got1[8];
        for (;;) {
            bool o = true;
#pragma unroll
            for (int p = 0; p < 8; p++) {
                got0[p] = __hip_atomic_load(&crd[(p << 9) + col0], __ATOMIC_RELAXED,
                                            __HIP_MEMORY_SCOPE_AGENT);
                got1[p] = __hip_atomic_load(&crd[(p << 9) + col1], __ATOMIC_RELAXED,
                                            __HIP_MEMORY_SCOPE_AGENT);
            }
#pragma unroll
            for (int p = 0; p < 8; p++)
                o = o && ((got0[p] & 0xFFFFu) == tag) && ((got1[p] & 0xFFFFu) == tag);
            if (o) break;
            __builtin_amdgcn_s_sleep(1);
        }
        float r0 = 0.f, r1 = 0.f;
#pragma unroll
        for (int p = 0; p < 8; p++) {
            r0 += __uint_as_float(got0[p] & 0xFFFF0000u);
            r1 += __uint_as_float(got1[p] & 0xFFFF0000u);
        }
        float q0 = MARG / r0; if (!isfinite(q0)) q0 = MARG;
        float q1 = MARG / r1; if (!isfinite(q1)) q1 = MARG;
        v_s[col0] = q0;
        v_s[col1] = q1;
    }
    __syncthreads();
    float vr[8];
#pragma unroll
    for (int k = 0; k < 8; ++k) vr[k] = v_s[lane * 8 + k];
    float acc = 0.f;
#pragma unroll
    for (int r = 0; r < 16; ++r) {
        float u_r = u_loc[r];
        uint4 pv = pw[r];
        float f[8];
        f[0] = bf2f_lo(pv.x); f[1] = bf2f_hi(pv.x);
        f[2] = bf2f_lo(pv.y); f[3] = bf2f_hi(pv.y);
        f[4] = bf2f_lo(pv.z); f[5] = bf2f_hi(pv.z);
        f[6] = bf2f_lo(pv.w); f[7] = bf2f_hi(pv.w);
#pragma unroll
        for (int k = 0; k < 8; ++k) {
            float p = f[k];
            acc += u_r * p * vr[k] * (-0.1f) * logf(p);   // C = -log(P0)/10
        }
    }
    acc = wred64(acc);
    if (lane == 0) bs[w] = acc;
    __syncthreads();
    if (t == 0) {
        float c = (bs[0] + bs[1] + bs[2] + bs[3]) * (1.0f / 64.0f);   // /B
        atomicAdd(&outf[1], c);
        atomicAdd(&outf[2], c);
    }
}

extern "C" void kernel_launch(void* const* d_in, const int* in_sizes, int n_in,
                              void* d_out, int out_size, void* d_ws, size_t ws_size,
                              hipStream_t stream) {
    const void* sg = d_in[0];
    const void* qg = d_in[1];
    const void* an = d_in[2];
    const void* bn = d_in[3];
    char* ws = (char*)d_ws;
    float* outf = (float*)d_out;                     // output dtype: float32 x3

    float* simg     = (float*)(ws + O_SIMG);
    float* rnan     = (float*)(ws + O_RNAN);
    float* rnbn     = (float*)(ws + O_RNBN);
    unsigned* colp  = (unsigned*)(ws + O_COLP);      // 4 tagged banks
    unsigned short* p0 = (unsigned short*)(ws + O_P0);

    k_rnormAB<<<16384, 256, 0, stream>>>(an, bn, rnan, rnbn);
    k_simg<<<16, 256, 0, stream>>>(sg, qg, simg);
    k_gloss<<<1, 256, 0, stream>>>(simg, outf);
    k_build<<<dim3(16, 64), 256, 0, stream>>>(an, bn, rnan, rnbn, p0);
    k_persist<<<512, 256, 0, stream>>>(p0, colp, outf);
}